// Round 1
// baseline (175.452 us; speedup 1.0000x reference)
//
#include <hip/hip_runtime.h>

#define NB 2
#define NN 64
#define NE 128
#define NH 8
#define ND 16
#define NC 64          // E/2
#define NROWS (NB*NN*NN)  // 8192

// Kernel 1: LayerNorm(pair_emb) + 4 projections: q*scale, k_e, v_e, gate.
// 16 rows per block, 256 threads.
__global__ __launch_bounds__(256) void tri_k1(
    const float* __restrict__ pair_emb,
    const float* __restrict__ ln_g, const float* __restrict__ ln_b,
    const float* __restrict__ Wq, const float* __restrict__ bq,
    const float* __restrict__ Wke, const float* __restrict__ bke,
    const float* __restrict__ Wv, const float* __restrict__ bv,
    const float* __restrict__ Wg, const float* __restrict__ bg,
    float* __restrict__ qo, float* __restrict__ keo,
    float* __restrict__ veo, float* __restrict__ gateo)
{
    __shared__ float pe_s[16][NE];
    const int tid = threadIdx.x;
    const int wave = tid >> 6, lane = tid & 63;
    const int row0 = blockIdx.x * 16;

    // LayerNorm: each wave handles 4 rows; 2 elems/lane.
    for (int r = wave * 4; r < wave * 4 + 4; ++r) {
        const int row = row0 + r;
        float2 v = *reinterpret_cast<const float2*>(&pair_emb[(size_t)row * NE + lane * 2]);
        float s = v.x + v.y, s2 = v.x * v.x + v.y * v.y;
        #pragma unroll
        for (int m = 1; m < 64; m <<= 1) { s += __shfl_xor(s, m); s2 += __shfl_xor(s2, m); }
        const float mean = s * (1.0f / NE);
        const float var = fmaxf(s2 * (1.0f / NE) - mean * mean, 0.0f);
        const float inv = rsqrtf(var + 1e-5f);
        pe_s[r][lane * 2]     = (v.x - mean) * inv * ln_g[lane * 2]     + ln_b[lane * 2];
        pe_s[r][lane * 2 + 1] = (v.y - mean) * inv * ln_g[lane * 2 + 1] + ln_b[lane * 2 + 1];
    }
    __syncthreads();

    // 4 GEMVs per row: thread o computes col o for 8 rows (half selects rows).
    const int o = tid & 127;
    const int half = tid >> 7;
    float aq[8] = {0,0,0,0,0,0,0,0}, ak[8] = {0,0,0,0,0,0,0,0};
    float av[8] = {0,0,0,0,0,0,0,0}, ag[8] = {0,0,0,0,0,0,0,0};
    for (int c = 0; c < NE; ++c) {
        const float wq = Wq[c * NE + o];
        const float wk = Wke[c * NE + o];
        const float wv = Wv[c * NE + o];
        const float wg = Wg[c * NE + o];
        #pragma unroll
        for (int r = 0; r < 8; ++r) {
            const float p = pe_s[half * 8 + r][c];
            aq[r] += p * wq; ak[r] += p * wk; av[r] += p * wv; ag[r] += p * wg;
        }
    }
    #pragma unroll
    for (int r = 0; r < 8; ++r) {
        const size_t row = (size_t)row0 + half * 8 + r;
        qo[row * NE + o]    = (aq[r] + bq[o]) * 0.25f;   // scale = 1/sqrt(D)=0.25
        keo[row * NE + o]   = ak[r] + bke[o];
        veo[row * NE + o]   = av[r] + bv[o];
        gateo[row * NE + o] = 1.0f / (1.0f + __expf(-(ag[r] + bg[o])));
    }
}

// Kernel 2: one block per (b,i,x). 256 threads.
__global__ __launch_bounds__(256) void tri_k2(
    const float* __restrict__ tri, const float* __restrict__ mask,
    const float* __restrict__ qv, const float* __restrict__ kev,
    const float* __restrict__ vev, const float* __restrict__ gatev,
    const float* __restrict__ Wka, const float* __restrict__ bka,
    const float* __restrict__ Wva, const float* __restrict__ bva,
    const float* __restrict__ Wo, const float* __restrict__ bo,
    float* __restrict__ out)
{
    __shared__ float tri_s[64][68];   // [j][c], padded stride 68 (bank spread, 16B aligned rows)
    __shared__ float q_s[NE];
    __shared__ float qw_s[8][68];     // Wka^T projected q: [h][c]
    __shared__ float sc_s[8][72];     // scores then attn: [h][j]
    __shared__ float t_s[8][68];      // attn^T @ tri: [h][c]
    __shared__ float o_s[NE];
    __shared__ float bias_s[64];
    __shared__ float qb_s[8];

    const int tid = threadIdx.x;
    const int bix = blockIdx.x;
    const int b = bix >> 12;
    const int x = bix & 63;
    const int base_bi = bix - x;      // flat row of (b,i,0)

    if (tid < NE) q_s[tid] = qv[(size_t)bix * NE + tid];
    if (tid >= 128 && tid < 192) {
        const int j = tid - 128;
        bias_s[j] = (1.0f - mask[(size_t)(b * NN + j) * NN + x]) * 1e-9f;
    }
    // stage tri tile [64 j][64 c] (16 KB), 4 float4 per thread
    const float4* tri4 = reinterpret_cast<const float4*>(tri) + (size_t)bix * 1024;
    #pragma unroll
    for (int k = 0; k < 4; ++k) {
        const int v = tid + k * 256;
        const int j = v >> 4, c4 = (v & 15) * 4;
        *reinterpret_cast<float4*>(&tri_s[j][c4]) = tri4[v];
    }
    __syncthreads();

    // qw[h][c] = sum_d q[h,d] * Wka[c, h*16+d]; qb[h] = q[h,:]·bka[h-slice]
    #pragma unroll
    for (int u = 0; u < 2; ++u) {
        const int p = tid + u * 256;
        const int h = p >> 6, c = p & 63;
        const float4* w4 = reinterpret_cast<const float4*>(&Wka[(size_t)c * NE + h * ND]);
        const float4* q4 = reinterpret_cast<const float4*>(&q_s[h * ND]);
        float acc = 0.0f;
        #pragma unroll
        for (int d4 = 0; d4 < 4; ++d4) {
            const float4 w = w4[d4], q = q4[d4];
            acc += w.x * q.x + w.y * q.y + w.z * q.z + w.w * q.w;
        }
        qw_s[h][c] = acc;
    }
    if (tid < 8) {
        float acc = 0.0f;
        for (int d = 0; d < ND; ++d) acc += q_s[tid * ND + d] * bka[tid * ND + d];
        qb_s[tid] = acc;
    }
    __syncthreads();

    // scores[h][j] = q·k_e + tri[j]·qw[h] + qb[h] + bias[j]; thread: (h, j0) and (h, j0+32)
    {
        const int h = tid & 7, j0 = tid >> 3;
        float4 qq[4];
        const float4* q4 = reinterpret_cast<const float4*>(&q_s[h * ND]);
        #pragma unroll
        for (int d4 = 0; d4 < 4; ++d4) qq[d4] = q4[d4];
        const float4* ke0 = reinterpret_cast<const float4*>(&kev[(size_t)(base_bi + j0) * NE + h * ND]);
        const float4* ke1 = reinterpret_cast<const float4*>(&kev[(size_t)(base_bi + j0 + 32) * NE + h * ND]);
        float a0 = qb_s[h] + bias_s[j0];
        float a1 = qb_s[h] + bias_s[j0 + 32];
        #pragma unroll
        for (int d4 = 0; d4 < 4; ++d4) {
            const float4 k0 = ke0[d4], k1 = ke1[d4];
            a0 += k0.x * qq[d4].x + k0.y * qq[d4].y + k0.z * qq[d4].z + k0.w * qq[d4].w;
            a1 += k1.x * qq[d4].x + k1.y * qq[d4].y + k1.z * qq[d4].z + k1.w * qq[d4].w;
        }
        #pragma unroll 4
        for (int c4 = 0; c4 < 64; c4 += 4) {
            const float4 w  = *reinterpret_cast<const float4*>(&qw_s[h][c4]);
            const float4 t0 = *reinterpret_cast<const float4*>(&tri_s[j0][c4]);
            const float4 t1 = *reinterpret_cast<const float4*>(&tri_s[j0 + 32][c4]);
            a0 += t0.x * w.x + t0.y * w.y + t0.z * w.z + t0.w * w.w;
            a1 += t1.x * w.x + t1.y * w.y + t1.z * w.z + t1.w * w.w;
        }
        sc_s[h][j0] = a0;
        sc_s[h][j0 + 32] = a1;
    }
    __syncthreads();

    // softmax over j per h: 32 lanes per h, 2 j each; shfl_xor<32 stays in-group
    {
        const int hh = tid >> 5, l = tid & 31;
        const float v0 = sc_s[hh][l], v1 = sc_s[hh][l + 32];
        float m = fmaxf(v0, v1);
        #pragma unroll
        for (int msk = 1; msk < 32; msk <<= 1) m = fmaxf(m, __shfl_xor(m, msk));
        const float e0 = __expf(v0 - m), e1 = __expf(v1 - m);
        float s = e0 + e1;
        #pragma unroll
        for (int msk = 1; msk < 32; msk <<= 1) s += __shfl_xor(s, msk);
        const float inv = 1.0f / s;
        sc_s[hh][l] = e0 * inv;
        sc_s[hh][l + 32] = e1 * inv;
    }
    __syncthreads();

    // t[h][c] = sum_j attn[h][j] * tri[j][c]; thread: (c, h2) and (c, h2+4)
    {
        const int c = tid & 63, h2 = tid >> 6;
        float acc0 = 0.0f, acc1 = 0.0f;
        for (int j = 0; j < 64; ++j) {
            const float tv = tri_s[j][c];
            acc0 += sc_s[h2][j] * tv;
            acc1 += sc_s[h2 + 4][j] * tv;
        }
        t_s[h2][c] = acc0;
        t_s[h2 + 4][c] = acc1;
    }
    __syncthreads();

    // o[h*16+d] = t[h]·Wva[:,h*16+d] + bva + sum_j attn[h][j]*v_e[j][h*16+d]
    if (tid < NE) {
        const int hh = tid >> 4;
        float acc = bva[tid];
        #pragma unroll 4
        for (int c = 0; c < NC; ++c) acc += t_s[hh][c] * Wva[(size_t)c * NE + tid];
        #pragma unroll 4
        for (int j = 0; j < 64; ++j) acc += sc_s[hh][j] * vev[(size_t)(base_bi + j) * NE + tid];
        o_s[tid] = acc;
    }
    __syncthreads();

    // out = (o @ Wo + bo) * gate
    if (tid < NE) {
        float acc = bo[tid];
        #pragma unroll 4
        for (int e = 0; e < NE; ++e) acc += o_s[e] * Wo[(size_t)e * NE + tid];
        out[(size_t)bix * NE + tid] = acc * gatev[(size_t)bix * NE + tid];
    }
}

extern "C" void kernel_launch(void* const* d_in, const int* in_sizes, int n_in,
                              void* d_out, int out_size, void* d_ws, size_t ws_size,
                              hipStream_t stream)
{
    const float* pair_emb = (const float*)d_in[0];
    const float* tri_emb  = (const float*)d_in[1];
    const float* mask     = (const float*)d_in[2];
    const float* ln_g = (const float*)d_in[3];
    const float* ln_b = (const float*)d_in[4];
    const float* Wq  = (const float*)d_in[5];  const float* bq  = (const float*)d_in[6];
    const float* Wke = (const float*)d_in[7];  const float* bke = (const float*)d_in[8];
    const float* Wka = (const float*)d_in[9];  const float* bka = (const float*)d_in[10];
    const float* Wv  = (const float*)d_in[11]; const float* bv  = (const float*)d_in[12];
    const float* Wva = (const float*)d_in[13]; const float* bva = (const float*)d_in[14];
    const float* Wo  = (const float*)d_in[15]; const float* bo  = (const float*)d_in[16];
    const float* Wg  = (const float*)d_in[17]; const float* bg  = (const float*)d_in[18];

    // workspace: 4 f32 arrays of [8192][128] = 16 MB total
    float* ws = (float*)d_ws;
    float* qo    = ws;
    float* keo   = ws + (size_t)NROWS * NE;
    float* veo   = ws + 2 * (size_t)NROWS * NE;
    float* gateo = ws + 3 * (size_t)NROWS * NE;

    hipLaunchKernelGGL(tri_k1, dim3(NROWS / 16), dim3(256), 0, stream,
        pair_emb, ln_g, ln_b, Wq, bq, Wke, bke, Wv, bv, Wg, bg,
        qo, keo, veo, gateo);
    hipLaunchKernelGGL(tri_k2, dim3(NROWS), dim3(256), 0, stream,
        tri_emb, mask, qo, keo, veo, gateo, Wka, bka, Wva, bva, Wo, bo,
        (float*)d_out);
}

// Round 2
// 148.476 us; speedup vs baseline: 1.1817x; 1.1817x over previous
//
#include <hip/hip_runtime.h>

#define NB 2
#define NN 64
#define NE 128
#define NH 8
#define ND 16
#define NC 64          // E/2
#define NROWS (NB*NN*NN)  // 8192

// ---------------- k1: LayerNorm + 4 projections (q*scale, k_e, v_e, gate) ----------------
__global__ __launch_bounds__(256) void tri_k1(
    const float* __restrict__ pair_emb,
    const float* __restrict__ ln_g, const float* __restrict__ ln_b,
    const float* __restrict__ Wq, const float* __restrict__ bq,
    const float* __restrict__ Wke, const float* __restrict__ bke,
    const float* __restrict__ Wv, const float* __restrict__ bv,
    const float* __restrict__ Wg, const float* __restrict__ bg,
    float* __restrict__ qo, float* __restrict__ keo,
    float* __restrict__ veo, float* __restrict__ gateo)
{
    __shared__ float pe_s[16][NE];
    const int tid = threadIdx.x;
    const int wave = tid >> 6, lane = tid & 63;
    const int row0 = blockIdx.x * 16;

    for (int r = wave * 4; r < wave * 4 + 4; ++r) {
        const int row = row0 + r;
        float2 v = *reinterpret_cast<const float2*>(&pair_emb[(size_t)row * NE + lane * 2]);
        float s = v.x + v.y, s2 = v.x * v.x + v.y * v.y;
        #pragma unroll
        for (int m = 1; m < 64; m <<= 1) { s += __shfl_xor(s, m); s2 += __shfl_xor(s2, m); }
        const float mean = s * (1.0f / NE);
        const float var = fmaxf(s2 * (1.0f / NE) - mean * mean, 0.0f);
        const float inv = rsqrtf(var + 1e-5f);
        pe_s[r][lane * 2]     = (v.x - mean) * inv * ln_g[lane * 2]     + ln_b[lane * 2];
        pe_s[r][lane * 2 + 1] = (v.y - mean) * inv * ln_g[lane * 2 + 1] + ln_b[lane * 2 + 1];
    }
    __syncthreads();

    const int o = tid & 127;
    const int half = tid >> 7;
    float aq[8] = {0,0,0,0,0,0,0,0}, ak[8] = {0,0,0,0,0,0,0,0};
    float av[8] = {0,0,0,0,0,0,0,0}, ag[8] = {0,0,0,0,0,0,0,0};
    for (int c = 0; c < NE; ++c) {
        const float wq = Wq[c * NE + o];
        const float wk = Wke[c * NE + o];
        const float wv = Wv[c * NE + o];
        const float wg = Wg[c * NE + o];
        #pragma unroll
        for (int r = 0; r < 8; ++r) {
            const float p = pe_s[half * 8 + r][c];
            aq[r] += p * wq; ak[r] += p * wk; av[r] += p * wv; ag[r] += p * wg;
        }
    }
    #pragma unroll
    for (int r = 0; r < 8; ++r) {
        const size_t row = (size_t)row0 + half * 8 + r;
        qo[row * NE + o]    = (aq[r] + bq[o]) * 0.25f;
        keo[row * NE + o]   = ak[r] + bke[o];
        veo[row * NE + o]   = av[r] + bv[o];
        gateo[row * NE + o] = 1.0f / (1.0f + __expf(-(ag[r] + bg[o])));
    }
}

// ---------------- k1b: per (b,i): S0[x,h,j] = q·k_e + q·bka + bias ; qw[x,h,c] = Wka^T q ----
__global__ __launch_bounds__(256) void tri_k1b(
    const float* __restrict__ qv, const float* __restrict__ kev,
    const float* __restrict__ mask,
    const float* __restrict__ Wka, const float* __restrict__ bka,
    float* __restrict__ S0g, float* __restrict__ qwg)
{
    __shared__ float qt[NN][129];     // padded: per-x scalar reads conflict-free
    __shared__ float ket[NN][NE];
    __shared__ float wka_s[NC][NE];
    __shared__ float msk[NN][NN];     // [j][x]
    __shared__ float bka_s[NE];

    const int tid = threadIdx.x;
    const int blk = blockIdx.x;       // (b,i), 0..127
    const int b = blk >> 6;
    const size_t base = (size_t)blk * NN;

    #pragma unroll
    for (int k = 0; k < 8; ++k) {
        const int v = tid + k * 256;
        const int r = v >> 5, c4 = (v & 31) * 4;
        float4 t = *reinterpret_cast<const float4*>(&qv[(base + r) * NE + c4]);
        qt[r][c4 + 0] = t.x; qt[r][c4 + 1] = t.y; qt[r][c4 + 2] = t.z; qt[r][c4 + 3] = t.w;
        *reinterpret_cast<float4*>(&ket[r][c4]) =
            *reinterpret_cast<const float4*>(&kev[(base + r) * NE + c4]);
        *reinterpret_cast<float4*>(&wka_s[r][c4]) =
            *reinterpret_cast<const float4*>(&Wka[(size_t)r * NE + c4]);
    }
    #pragma unroll
    for (int k = 0; k < 4; ++k) {
        const int v = tid + k * 256;
        const int j = v >> 4, x4 = (v & 15) * 4;
        *reinterpret_cast<float4*>(&msk[j][x4]) =
            *reinterpret_cast<const float4*>(&mask[(size_t)b * 4096 + j * 64 + x4]);
    }
    if (tid < 32) {
        *reinterpret_cast<float4*>(&bka_s[tid * 4]) =
            *reinterpret_cast<const float4*>(&bka[tid * 4]);
    }
    __syncthreads();

    const int x2 = tid & 31, h = tid >> 5;
    const int xA = x2, xB = x2 + 32;
    float qA[16], qB[16];
    #pragma unroll
    for (int d = 0; d < 16; ++d) { qA[d] = qt[xA][h * 16 + d]; qB[d] = qt[xB][h * 16 + d]; }
    float qbA = 0.0f, qbB = 0.0f;
    #pragma unroll
    for (int d = 0; d < 16; ++d) { const float bk = bka_s[h * 16 + d]; qbA += qA[d] * bk; qbB += qB[d] * bk; }

    // S0 phase
    for (int j4 = 0; j4 < 16; ++j4) {
        float sA[4], sB[4];
        #pragma unroll
        for (int jj = 0; jj < 4; ++jj) {
            const int j = j4 * 4 + jj;
            float aA = qbA + 1e-9f * (1.0f - msk[j][xA]);
            float aB = qbB + 1e-9f * (1.0f - msk[j][xB]);
            const float4* kj = reinterpret_cast<const float4*>(&ket[j][h * 16]);
            #pragma unroll
            for (int d4 = 0; d4 < 4; ++d4) {
                const float4 kv = kj[d4];
                aA += qA[d4*4+0]*kv.x + qA[d4*4+1]*kv.y + qA[d4*4+2]*kv.z + qA[d4*4+3]*kv.w;
                aB += qB[d4*4+0]*kv.x + qB[d4*4+1]*kv.y + qB[d4*4+2]*kv.z + qB[d4*4+3]*kv.w;
            }
            sA[jj] = aA; sB[jj] = aB;
        }
        *reinterpret_cast<float4*>(&S0g[(base + xA) * 512 + h * 64 + j4 * 4]) =
            make_float4(sA[0], sA[1], sA[2], sA[3]);
        *reinterpret_cast<float4*>(&S0g[(base + xB) * 512 + h * 64 + j4 * 4]) =
            make_float4(sB[0], sB[1], sB[2], sB[3]);
    }
    // qw phase
    for (int c4 = 0; c4 < 16; ++c4) {
        float sA[4], sB[4];
        #pragma unroll
        for (int cc = 0; cc < 4; ++cc) {
            const int c = c4 * 4 + cc;
            float aA = 0.0f, aB = 0.0f;
            const float4* wj = reinterpret_cast<const float4*>(&wka_s[c][h * 16]);
            #pragma unroll
            for (int d4 = 0; d4 < 4; ++d4) {
                const float4 wv = wj[d4];
                aA += qA[d4*4+0]*wv.x + qA[d4*4+1]*wv.y + qA[d4*4+2]*wv.z + qA[d4*4+3]*wv.w;
                aB += qB[d4*4+0]*wv.x + qB[d4*4+1]*wv.y + qB[d4*4+2]*wv.z + qB[d4*4+3]*wv.w;
            }
            sA[cc] = aA; sB[cc] = aB;
        }
        *reinterpret_cast<float4*>(&qwg[(base + xA) * 512 + h * 64 + c4 * 4]) =
            make_float4(sA[0], sA[1], sA[2], sA[3]);
        *reinterpret_cast<float4*>(&qwg[(base + xB) * 512 + h * 64 + c4 * 4]) =
            make_float4(sB[0], sB[1], sB[2], sB[3]);
    }
}

// ---------------- k2: per (b,i,x): scores -> softmax -> t = attn^T tri ; pre = attn·v_e ----
__global__ __launch_bounds__(256) void tri_k2(
    const float* __restrict__ tri, const float* __restrict__ S0g,
    const float* __restrict__ qwg, const float* __restrict__ vev,
    float* __restrict__ tg, float* __restrict__ preg)
{
    __shared__ float tri_s[64][68];
    __shared__ float qw_s[8][68];
    __shared__ float sc_s[8][72];
    __shared__ float pre_p[2][128];

    const int tid = threadIdx.x;
    const int bix = blockIdx.x;
    const int base_bi = bix & ~63;

    const float4* tri4 = reinterpret_cast<const float4*>(tri) + (size_t)bix * 1024;
    #pragma unroll
    for (int k = 0; k < 4; ++k) {
        const int v = tid + k * 256;
        const int j = v >> 4, c4 = (v & 15) * 4;
        *reinterpret_cast<float4*>(&tri_s[j][c4]) = tri4[v];
    }
    {
        const int i0 = tid, i1 = tid + 256;
        qw_s[i0 >> 6][i0 & 63] = qwg[(size_t)bix * 512 + i0];
        qw_s[i1 >> 6][i1 & 63] = qwg[(size_t)bix * 512 + i1];
        sc_s[i0 >> 6][i0 & 63] = S0g[(size_t)bix * 512 + i0];
        sc_s[i1 >> 6][i1 & 63] = S0g[(size_t)bix * 512 + i1];
    }
    __syncthreads();

    // scores = S0 + tri·qw
    {
        const int h = tid & 7, j0 = tid >> 3;
        float a0 = sc_s[h][j0], a1 = sc_s[h][j0 + 32];
        #pragma unroll 4
        for (int c4 = 0; c4 < 64; c4 += 4) {
            const float4 w  = *reinterpret_cast<const float4*>(&qw_s[h][c4]);
            const float4 t0 = *reinterpret_cast<const float4*>(&tri_s[j0][c4]);
            const float4 t1 = *reinterpret_cast<const float4*>(&tri_s[j0 + 32][c4]);
            a0 += t0.x * w.x + t0.y * w.y + t0.z * w.z + t0.w * w.w;
            a1 += t1.x * w.x + t1.y * w.y + t1.z * w.z + t1.w * w.w;
        }
        sc_s[h][j0] = a0;
        sc_s[h][j0 + 32] = a1;
    }
    __syncthreads();

    // softmax over j per h
    {
        const int hh = tid >> 5, l = tid & 31;
        const float v0 = sc_s[hh][l], v1 = sc_s[hh][l + 32];
        float m = fmaxf(v0, v1);
        #pragma unroll
        for (int msk = 1; msk < 32; msk <<= 1) m = fmaxf(m, __shfl_xor(m, msk));
        const float e0 = __expf(v0 - m), e1 = __expf(v1 - m);
        float s = e0 + e1;
        #pragma unroll
        for (int msk = 1; msk < 32; msk <<= 1) s += __shfl_xor(s, msk);
        const float inv = 1.0f / s;
        sc_s[hh][l] = e0 * inv;
        sc_s[hh][l + 32] = e1 * inv;
    }
    __syncthreads();

    // t[h][c] = sum_j attn[h][j] tri[j][c] -> tg (coalesced: idx tid, tid+256)
    {
        const int c = tid & 63, h2 = tid >> 6;
        float acc0 = 0.0f, acc1 = 0.0f;
        #pragma unroll 8
        for (int j = 0; j < 64; ++j) {
            const float tv = tri_s[j][c];
            acc0 += sc_s[h2][j] * tv;
            acc1 += sc_s[h2 + 4][j] * tv;
        }
        tg[(size_t)bix * 512 + tid]       = acc0;
        tg[(size_t)bix * 512 + tid + 256] = acc1;
    }
    // pre[e] = sum_j attn[h(e)][j] v_e[j][e]  (split j over 2 groups)
    {
        const int e = tid & 127, g = tid >> 7;
        const int hh = e >> 4;
        float acc = 0.0f;
        #pragma unroll 4
        for (int j = g * 32; j < g * 32 + 32; ++j)
            acc += sc_s[hh][j] * vev[(size_t)(base_bi + j) * NE + e];
        pre_p[g][e] = acc;
    }
    __syncthreads();
    if (tid < 128) preg[(size_t)bix * NE + tid] = pre_p[0][tid] + pre_p[1][tid];
}

// ---------------- k3: out = ((pre + bva + t@Wva) @ Wo + bo) * gate ----------------
__global__ __launch_bounds__(256) void tri_k3(
    const float* __restrict__ tg, const float* __restrict__ preg,
    const float* __restrict__ gatev,
    const float* __restrict__ Wva, const float* __restrict__ bva,
    const float* __restrict__ Wo, const float* __restrict__ bo,
    float* __restrict__ out)
{
    __shared__ float wva_s[64][160];   // gapped: col(e) = e + 4*(e/16) -> conflict-free h-slices
    __shared__ float wo_s[128][128];
    __shared__ float o_s[32][132];

    const int tid = threadIdx.x;
    const int row0 = blockIdx.x * 32;

    #pragma unroll
    for (int k = 0; k < 8; ++k) {
        const int v = tid + k * 256;
        const int c = v >> 5, e4 = (v & 31) * 4;
        const int col = e4 + ((e4 >> 4) << 2);
        *reinterpret_cast<float4*>(&wva_s[c][col]) =
            *reinterpret_cast<const float4*>(&Wva[(size_t)c * NE + e4]);
    }
    #pragma unroll
    for (int k = 0; k < 16; ++k) {
        const int v = tid + k * 256;
        const int kk = v >> 5, e4 = (v & 31) * 4;
        *reinterpret_cast<float4*>(&wo_s[kk][e4]) =
            *reinterpret_cast<const float4*>(&Wo[(size_t)kk * NE + e4]);
    }
    __syncthreads();

    // Phase A: o[r][h*16+d] = pre + bva + sum_c t[r][h][c] * Wva[c][h*16+d]
    {
        const int r = tid >> 3, h = tid & 7;
        const size_t row = (size_t)row0 + r;
        float4 acc[4];
        #pragma unroll
        for (int d4 = 0; d4 < 4; ++d4) {
            const float4 p  = *reinterpret_cast<const float4*>(&preg[row * NE + h * 16 + d4 * 4]);
            const float4 bv = *reinterpret_cast<const float4*>(&bva[h * 16 + d4 * 4]);
            acc[d4].x = p.x + bv.x; acc[d4].y = p.y + bv.y;
            acc[d4].z = p.z + bv.z; acc[d4].w = p.w + bv.w;
        }
        const float4* tp = reinterpret_cast<const float4*>(&tg[row * 512 + h * 64]);
        for (int c4 = 0; c4 < 16; ++c4) {
            const float4 tv = tp[c4];
            const float tc[4] = {tv.x, tv.y, tv.z, tv.w};
            #pragma unroll
            for (int cc = 0; cc < 4; ++cc) {
                const int c = c4 * 4 + cc;
                const float t0 = tc[cc];
                #pragma unroll
                for (int d4 = 0; d4 < 4; ++d4) {
                    const float4 w = *reinterpret_cast<const float4*>(&wva_s[c][20 * h + d4 * 4]);
                    acc[d4].x += t0 * w.x; acc[d4].y += t0 * w.y;
                    acc[d4].z += t0 * w.z; acc[d4].w += t0 * w.w;
                }
            }
        }
        #pragma unroll
        for (int d4 = 0; d4 < 4; ++d4)
            *reinterpret_cast<float4*>(&o_s[r][h * 16 + d4 * 4]) = acc[d4];
    }
    __syncthreads();

    // Phase B: out[r][e] = (sum_k o[r][k] Wo[k][e] + bo[e]) * gate[r][e]
    {
        const int e4 = (tid & 31) * 4, rg = tid >> 5;
        const float4 b4 = *reinterpret_cast<const float4*>(&bo[e4]);
        float4 acc[4];
        #pragma unroll
        for (int rr = 0; rr < 4; ++rr) acc[rr] = b4;
        #pragma unroll 4
        for (int k = 0; k < 128; ++k) {
            const float4 w = *reinterpret_cast<const float4*>(&wo_s[k][e4]);
            #pragma unroll
            for (int rr = 0; rr < 4; ++rr) {
                const float ov = o_s[rg * 4 + rr][k];
                acc[rr].x += ov * w.x; acc[rr].y += ov * w.y;
                acc[rr].z += ov * w.z; acc[rr].w += ov * w.w;
            }
        }
        #pragma unroll
        for (int rr = 0; rr < 4; ++rr) {
            const size_t row = (size_t)row0 + rg * 4 + rr;
            const float4 g = *reinterpret_cast<const float4*>(&gatev[row * NE + e4]);
            float4 o;
            o.x = acc[rr].x * g.x; o.y = acc[rr].y * g.y;
            o.z = acc[rr].z * g.z; o.w = acc[rr].w * g.w;
            *reinterpret_cast<float4*>(&out[row * NE + e4]) = o;
        }
    }
}

extern "C" void kernel_launch(void* const* d_in, const int* in_sizes, int n_in,
                              void* d_out, int out_size, void* d_ws, size_t ws_size,
                              hipStream_t stream)
{
    const float* pair_emb = (const float*)d_in[0];
    const float* tri_emb  = (const float*)d_in[1];
    const float* mask     = (const float*)d_in[2];
    const float* ln_g = (const float*)d_in[3];
    const float* ln_b = (const float*)d_in[4];
    const float* Wq  = (const float*)d_in[5];  const float* bq  = (const float*)d_in[6];
    const float* Wke = (const float*)d_in[7];  const float* bke = (const float*)d_in[8];
    const float* Wka = (const float*)d_in[9];  const float* bka = (const float*)d_in[10];
    const float* Wv  = (const float*)d_in[11]; const float* bv  = (const float*)d_in[12];
    const float* Wva = (const float*)d_in[13]; const float* bva = (const float*)d_in[14];
    const float* Wo  = (const float*)d_in[15]; const float* bo  = (const float*)d_in[16];
    const float* Wg  = (const float*)d_in[17]; const float* bg  = (const float*)d_in[18];

    float* ws = (float*)d_ws;
    float* qo    = ws;                               // 1M floats
    float* keo   = qo    + (size_t)NROWS * NE;       // 1M
    float* veo   = keo   + (size_t)NROWS * NE;       // 1M
    float* gateo = veo   + (size_t)NROWS * NE;       // 1M
    float* qwg   = gateo + (size_t)NROWS * NE;       // 4M
    float* S0g   = qwg   + (size_t)NROWS * 512;      // 4M
    float* tg    = S0g   + (size_t)NROWS * 512;      // 4M
    float* preg  = tg    + (size_t)NROWS * 512;      // 1M  -> total 68 MB

    hipLaunchKernelGGL(tri_k1, dim3(NROWS / 16), dim3(256), 0, stream,
        pair_emb, ln_g, ln_b, Wq, bq, Wke, bke, Wv, bv, Wg, bg,
        qo, keo, veo, gateo);
    hipLaunchKernelGGL(tri_k1b, dim3(NB * NN), dim3(256), 0, stream,
        qo, keo, mask, Wka, bka, S0g, qwg);
    hipLaunchKernelGGL(tri_k2, dim3(NROWS), dim3(256), 0, stream,
        tri_emb, S0g, qwg, veo, tg, preg);
    hipLaunchKernelGGL(tri_k3, dim3(NROWS / 32), dim3(256), 0, stream,
        tg, preg, gateo, Wva, bva, Wo, bo, (float*)d_out);
}